// Round 2
// baseline (278.908 us; speedup 1.0000x reference)
//
#include <hip/hip_runtime.h>

// Biaffine: out[b,x,y] = Daug[b,x,:]·U·H[b,y,:] + Daug[b,x,:]·W[:d+1] + H[b,y,:]·W[d+1:]
// B=32, S=512, d=1024.  bf16 MFMA two-stage GEMM:
//   T = D @ U[0:d,:] + U[d,:]            (16384 x 1024 x 1024, bf16 out)
//   out[b] = T[b] @ H[b]^T + linD + linH (32 x 512x512x1024, fp32 out)
// R2 changes: LDS layout [kchunk][row] (kills bank conflicts under the
// global_load_lds contiguous-dest constraint), BK=64 (32 MFMA per barrier),
// XCD-aware grid mapping (A-sharing blocks on one XCD; one batch per XCD).

#define D_DIM 1024
#define ROWS 16384   // B*S

typedef float floatx4 __attribute__((ext_vector_type(4)));
typedef __bf16 bf16x8 __attribute__((ext_vector_type(8)));

__device__ inline unsigned short f2bf(float f) {
  unsigned int u = __builtin_bit_cast(unsigned int, f);
  u = (u + 0x7FFFu + ((u >> 16) & 1u)) >> 16;   // round-nearest-even
  return (unsigned short)u;
}

__device__ inline void async_load16(const void* g, void* l) {
  __builtin_amdgcn_global_load_lds(
      (const __attribute__((address_space(1))) void*)g,
      (__attribute__((address_space(3))) void*)l, 16, 0, 0);
}

// ---- cast D/H to bf16 + fused linear-term dot products ----------------------
__global__ __launch_bounds__(256) void cast_rows_kernel(
    const float* __restrict__ D, const float* __restrict__ H,
    const float* __restrict__ W,
    unsigned short* __restrict__ Dbf, unsigned short* __restrict__ Hbf,
    float* __restrict__ linD, float* __restrict__ linH) {
  int rowid = blockIdx.x;
  bool isH = rowid >= ROWS;
  int r = isH ? rowid - ROWS : rowid;
  const float* src = (isH ? H : D) + (size_t)r * D_DIM;
  unsigned short* dst = (isH ? Hbf : Dbf) + (size_t)r * D_DIM;
  const float* w = W + (isH ? (D_DIM + 1) : 0);
  int t = threadIdx.x;                 // 256 threads, 4 elems each
  float4 v = ((const float4*)src)[t];
  float s = v.x * w[4*t] + v.y * w[4*t+1] + v.z * w[4*t+2] + v.w * w[4*t+3];
  ushort4 o;
  o.x = f2bf(v.x); o.y = f2bf(v.y); o.z = f2bf(v.z); o.w = f2bf(v.w);
  ((ushort4*)dst)[t] = o;
  #pragma unroll
  for (int off = 32; off > 0; off >>= 1) s += __shfl_down(s, off, 64);
  __shared__ float red[4];
  int wave = t >> 6;
  if ((t & 63) == 0) red[wave] = s;
  __syncthreads();
  if (t == 0) {
    float tot = red[0] + red[1] + red[2] + red[3];
    if (!isH) tot += W[D_DIM];         // ones-column bias for Daug side
    (isH ? linH : linD)[r] = tot;
  }
}

// ---- transpose U (first 1024 rows) to bf16 Ut[n][k] = U[k][n] ---------------
__global__ __launch_bounds__(256) void transU_kernel(
    const float* __restrict__ U, unsigned short* __restrict__ Ut) {
  __shared__ float tile[32][33];
  int n0 = blockIdx.x * 32;
  int k0 = blockIdx.y * 32;
  int t = threadIdx.x;
  int tr = t >> 5, tc = t & 31;
  #pragma unroll
  for (int i = 0; i < 32; i += 8)
    tile[tr + i][tc] = U[(size_t)(k0 + tr + i) * D_DIM + n0 + tc];
  __syncthreads();
  #pragma unroll
  for (int i = 0; i < 32; i += 8)
    Ut[(size_t)(n0 + tr + i) * D_DIM + k0 + tc] = f2bf(tile[tc][tr + i]);
}

// ---- shared MFMA K-loop core: 128x128 tile, BK=64 ---------------------------
// LDS layout: chunk index = q*128 + r, q = k-16B-chunk (0..7), r = tile row.
// Frag read addr = ((s*4+quad)*128 + row)*16B: 16 lanes of a quad stride 16B
// across rows -> full 32-bank coverage, minimum b128 phases.
__device__ inline void gemm_core_128(
    const unsigned short* __restrict__ A, const unsigned short* __restrict__ Bt,
    int m0, int n0, unsigned short* As, unsigned short* Bs,
    floatx4 (&acc)[4][4]) {
  const int K = D_DIM;
  int tid = threadIdx.x;
  int lane = tid & 63, wave = tid >> 6;
  int quad = lane >> 4, lrow = lane & 15;
  int wm = wave >> 1, wn = wave & 1;

  // staging: 1024 chunks (16B) per tile, 4 issues/thread/matrix
  int q0 = tid >> 7;            // issue i: chunk cc = i*256+tid -> q = cc>>7
  int rr0 = tid & 127;
  const unsigned short* gA = A + (size_t)(m0 + rr0) * K + q0 * 8;
  const unsigned short* gB = Bt + (size_t)(n0 + rr0) * K + q0 * 8;

  for (int k0 = 0; k0 < K; k0 += 64) {
    __syncthreads();
    #pragma unroll
    for (int i = 0; i < 4; ++i) {   // q = i*2 + q0
      async_load16(gA + k0 + i * 16, As + (i * 256 + tid) * 8);
      async_load16(gB + k0 + i * 16, Bs + (i * 256 + tid) * 8);
    }
    __syncthreads();
    #pragma unroll
    for (int s = 0; s < 2; ++s) {
      bf16x8 a[4], b[4];
      #pragma unroll
      for (int mt = 0; mt < 4; ++mt)
        a[mt] = *(const bf16x8*)(As + (((s * 4 + quad) * 128) + wm * 64 + mt * 16 + lrow) * 8);
      #pragma unroll
      for (int nt = 0; nt < 4; ++nt)
        b[nt] = *(const bf16x8*)(Bs + (((s * 4 + quad) * 128) + wn * 64 + nt * 16 + lrow) * 8);
      #pragma unroll
      for (int mt = 0; mt < 4; ++mt)
        #pragma unroll
        for (int nt = 0; nt < 4; ++nt)
          acc[mt][nt] = __builtin_amdgcn_mfma_f32_16x16x32_bf16(
              a[mt], b[nt], acc[mt][nt], 0, 0, 0);
    }
  }
}

// ---- GEMM1: T[m][n] = sum_k Dbf[m][k] * Ut[n][k] + Ubias[n], bf16 out -------
// grid (128, 8): blockIdx.x = m-tile (fastest) -> id%8 = mtile%8 -> all 8
// n-blocks sharing an A row-tile land on ONE XCD (A fetched once per XCD set).
__global__ __launch_bounds__(256) void gemm1_kernel(
    const unsigned short* __restrict__ A,    // [16384,1024] bf16 bits
    const unsigned short* __restrict__ Bt,   // [1024,1024]  bf16 bits
    const float* __restrict__ Ubias,         // fp32, len 1024
    unsigned short* __restrict__ T) {
  __shared__ __align__(16) unsigned short As[128 * 64];
  __shared__ __align__(16) unsigned short Bs[128 * 64];
  int m0 = blockIdx.x * 128, n0 = blockIdx.y * 128;
  int tid = threadIdx.x;
  int lane = tid & 63, wave = tid >> 6;
  int quad = lane >> 4, lrow = lane & 15;
  int wm = wave >> 1, wn = wave & 1;

  floatx4 acc[4][4] = {};
  gemm_core_128(A, Bt, m0, n0, As, Bs, acc);

  // C/D layout: col = lane&15, row = quad*4 + reg  [m89-verified]
  #pragma unroll
  for (int mt = 0; mt < 4; ++mt)
    #pragma unroll
    for (int nt = 0; nt < 4; ++nt) {
      int row = m0 + wm * 64 + mt * 16 + quad * 4;
      int col = n0 + wn * 64 + nt * 16 + lrow;
      float bias = Ubias[col];
      #pragma unroll
      for (int rr = 0; rr < 4; ++rr)
        T[(size_t)(row + rr) * D_DIM + col] = f2bf(acc[mt][nt][rr] + bias);
    }
}

// ---- GEMM2: out[b,x,y] = sum_k T[b,x,k]*Hbf[b,y,k] + linD[b,x] + linH[b,y] --
// grid (32, 16): blockIdx.x = batch (fastest) -> id%8 = b%8 -> each batch's
// 16 blocks on one XCD; T[b]+H[b] = 2 MB fits the 4 MB per-XCD L2.
__global__ __launch_bounds__(256) void gemm2_kernel(
    const unsigned short* __restrict__ Tg,   // [32*512,1024]
    const unsigned short* __restrict__ Hbf,  // [32*512,1024]
    const float* __restrict__ linD, const float* __restrict__ linH,
    float* __restrict__ out) {               // [32,512,512]
  __shared__ __align__(16) unsigned short As[128 * 64];
  __shared__ __align__(16) unsigned short Bs[128 * 64];
  int b = blockIdx.x;
  int t = blockIdx.y;
  int m0 = (t >> 2) * 128, n0 = (t & 3) * 128;
  const unsigned short* A = Tg + (size_t)b * 512 * D_DIM;
  const unsigned short* Bt = Hbf + (size_t)b * 512 * D_DIM;
  int tid = threadIdx.x;
  int lane = tid & 63, wave = tid >> 6;
  int quad = lane >> 4, lrow = lane & 15;
  int wm = wave >> 1, wn = wave & 1;

  floatx4 acc[4][4] = {};
  gemm_core_128(A, Bt, m0, n0, As, Bs, acc);

  #pragma unroll
  for (int mt = 0; mt < 4; ++mt)
    #pragma unroll
    for (int nt = 0; nt < 4; ++nt) {
      int row = m0 + wm * 64 + mt * 16 + quad * 4;
      int col = n0 + wn * 64 + nt * 16 + lrow;
      float lh = linH[b * 512 + col];
      #pragma unroll
      for (int rr = 0; rr < 4; ++rr) {
        float v = acc[mt][nt][rr] + linD[b * 512 + row + rr] + lh;
        out[((size_t)b * 512 + row + rr) * 512 + col] = v;
      }
    }
}

extern "C" void kernel_launch(void* const* d_in, const int* in_sizes, int n_in,
                              void* d_out, int out_size, void* d_ws, size_t ws_size,
                              hipStream_t stream) {
  const float* D = (const float*)d_in[0];
  const float* H = (const float*)d_in[1];
  const float* U = (const float*)d_in[2];   // [1025,1024]
  const float* W = (const float*)d_in[3];   // [2049]
  float* out = (float*)d_out;

  char* ws = (char*)d_ws;
  unsigned short* Dbf = (unsigned short*)ws; ws += (size_t)ROWS * D_DIM * 2;   // 32 MB
  unsigned short* Hbf = (unsigned short*)ws; ws += (size_t)ROWS * D_DIM * 2;   // 32 MB
  unsigned short* Tbf = (unsigned short*)ws; ws += (size_t)ROWS * D_DIM * 2;   // 32 MB
  unsigned short* Ut  = (unsigned short*)ws; ws += (size_t)D_DIM * D_DIM * 2;  //  2 MB
  float* linD = (float*)ws;                  ws += (size_t)ROWS * 4;
  float* linH = (float*)ws;                  ws += (size_t)ROWS * 4;

  cast_rows_kernel<<<dim3(2 * ROWS), 256, 0, stream>>>(D, H, W, Dbf, Hbf, linD, linH);
  transU_kernel<<<dim3(32, 32), 256, 0, stream>>>(U, Ut);
  gemm1_kernel<<<dim3(128, 8), 256, 0, stream>>>(Dbf, Ut, U + (size_t)D_DIM * D_DIM, Tbf);
  gemm2_kernel<<<dim3(32, 16), 256, 0, stream>>>(Tbf, Hbf, linD, linH, out);
}

// Round 3
// 222.980 us; speedup vs baseline: 1.2508x; 1.2508x over previous
//
#include <hip/hip_runtime.h>

// Biaffine: out[b,x,y] = Daug[b,x,:]·U·H[b,y,:] + Daug[b,x,:]·W[:d+1] + H[b,y,:]·W[d+1:]
// B=32, S=512, d=1024.  bf16 MFMA two-stage GEMM:
//   T = D @ U[0:d,:] + U[d,:]            (16384 x 1024 x 1024, bf16 out)
//   out[b] = T[b] @ H[b]^T + linD + linH (32 x 512x512x1024, fp32 out)
// R3: XOR-swizzled LDS layout — chunk(row,q) at g*64 + rl*8 + (q^rl)
// (g=row>>3, rl=row&7).  Staging instructions read 8 contiguous 128B lines
// (full coalescing, R1-style) AND frag reads stay bank-conflict-free
// (R2's win).  BK=64, XCD-aware grids kept.

#define D_DIM 1024
#define ROWS 16384   // B*S

typedef float floatx4 __attribute__((ext_vector_type(4)));
typedef __bf16 bf16x8 __attribute__((ext_vector_type(8)));

__device__ inline unsigned short f2bf(float f) {
  unsigned int u = __builtin_bit_cast(unsigned int, f);
  u = (u + 0x7FFFu + ((u >> 16) & 1u)) >> 16;   // round-nearest-even
  return (unsigned short)u;
}

__device__ inline void async_load16(const void* g, void* l) {
  __builtin_amdgcn_global_load_lds(
      (const __attribute__((address_space(1))) void*)g,
      (__attribute__((address_space(3))) void*)l, 16, 0, 0);
}

// ---- cast D/H to bf16 + fused linear-term dot products ----------------------
__global__ __launch_bounds__(256) void cast_rows_kernel(
    const float* __restrict__ D, const float* __restrict__ H,
    const float* __restrict__ W,
    unsigned short* __restrict__ Dbf, unsigned short* __restrict__ Hbf,
    float* __restrict__ linD, float* __restrict__ linH) {
  int rowid = blockIdx.x;
  bool isH = rowid >= ROWS;
  int r = isH ? rowid - ROWS : rowid;
  const float* src = (isH ? H : D) + (size_t)r * D_DIM;
  unsigned short* dst = (isH ? Hbf : Dbf) + (size_t)r * D_DIM;
  const float* w = W + (isH ? (D_DIM + 1) : 0);
  int t = threadIdx.x;                 // 256 threads, 4 elems each
  float4 v = ((const float4*)src)[t];
  float s = v.x * w[4*t] + v.y * w[4*t+1] + v.z * w[4*t+2] + v.w * w[4*t+3];
  ushort4 o;
  o.x = f2bf(v.x); o.y = f2bf(v.y); o.z = f2bf(v.z); o.w = f2bf(v.w);
  ((ushort4*)dst)[t] = o;
  #pragma unroll
  for (int off = 32; off > 0; off >>= 1) s += __shfl_down(s, off, 64);
  __shared__ float red[4];
  int wave = t >> 6;
  if ((t & 63) == 0) red[wave] = s;
  __syncthreads();
  if (t == 0) {
    float tot = red[0] + red[1] + red[2] + red[3];
    if (!isH) tot += W[D_DIM];         // ones-column bias for Daug side
    (isH ? linH : linD)[r] = tot;
  }
}

// ---- transpose U (first 1024 rows) to bf16 Ut[n][k] = U[k][n] ---------------
__global__ __launch_bounds__(256) void transU_kernel(
    const float* __restrict__ U, unsigned short* __restrict__ Ut) {
  __shared__ float tile[32][33];
  int n0 = blockIdx.x * 32;
  int k0 = blockIdx.y * 32;
  int t = threadIdx.x;
  int tr = t >> 5, tc = t & 31;
  #pragma unroll
  for (int i = 0; i < 32; i += 8)
    tile[tr + i][tc] = U[(size_t)(k0 + tr + i) * D_DIM + n0 + tc];
  __syncthreads();
  #pragma unroll
  for (int i = 0; i < 32; i += 8)
    Ut[(size_t)(n0 + tr + i) * D_DIM + k0 + tc] = f2bf(tile[tc][tr + i]);
}

// ---- swizzled MFMA K-loop core: 128x128 tile, BK=64 -------------------------
// LDS chunk (16B) for (row,q): c = (row>>3)*64 + (row&7)*8 + (q ^ (row&7)).
// Staging instr j (wave w): group g=j*4+w, lane l -> row 8g+(l>>3),
// q=(l&7)^(l>>3): 8 contiguous 128B global lines, LDS dest = base + lane*16.
// Frag read (row=W*64+mt*16+lrow, q=s*4+quad): 8-round minimum, no conflicts.
__device__ inline void gemm_core_swz(
    const unsigned short* __restrict__ A, const unsigned short* __restrict__ Bt,
    int m0, int n0, unsigned short* As, unsigned short* Bs,
    floatx4 (&acc)[4][4]) {
  const int K = D_DIM;
  int tid = threadIdx.x;
  int l = tid & 63, wave = tid >> 6;
  int quad = l >> 4, lrow = l & 15;
  int wm = wave >> 1, wn = wave & 1;

  int srow = 8 * wave + (l >> 3);              // +32*j per issue
  int sq = (l & 7) ^ (l >> 3);
  const unsigned short* gA = A + (size_t)(m0 + srow) * K + sq * 8;
  const unsigned short* gB = Bt + (size_t)(n0 + srow) * K + sq * 8;

  int rl = lrow & 7, gofs = lrow >> 3;
  int baseA = wm * 512 + gofs * 64 + rl * 8;
  int baseB = wn * 512 + gofs * 64 + rl * 8;

  for (int k0 = 0; k0 < K; k0 += 64) {
    __syncthreads();
    #pragma unroll
    for (int j = 0; j < 4; ++j) {
      async_load16(gA + (size_t)(32 * j) * K + k0, As + (j * 256 + tid) * 8);
      async_load16(gB + (size_t)(32 * j) * K + k0, Bs + (j * 256 + tid) * 8);
    }
    __syncthreads();
    #pragma unroll
    for (int s = 0; s < 2; ++s) {
      int xq = (s * 4 + quad) ^ rl;
      bf16x8 a[4], b[4];
      #pragma unroll
      for (int mt = 0; mt < 4; ++mt)
        a[mt] = *(const bf16x8*)(As + (baseA + mt * 128 + xq) * 8);
      #pragma unroll
      for (int nt = 0; nt < 4; ++nt)
        b[nt] = *(const bf16x8*)(Bs + (baseB + nt * 128 + xq) * 8);
      #pragma unroll
      for (int mt = 0; mt < 4; ++mt)
        #pragma unroll
        for (int nt = 0; nt < 4; ++nt)
          acc[mt][nt] = __builtin_amdgcn_mfma_f32_16x16x32_bf16(
              a[mt], b[nt], acc[mt][nt], 0, 0, 0);
    }
  }
}

// ---- GEMM1: T[m][n] = sum_k Dbf[m][k] * Ut[n][k] + Ubias[n], bf16 out -------
// grid (128, 8): id%8 = mtile%8 -> the 8 n-blocks sharing an A row-tile land
// on one XCD (A row-tile fetched once into that XCD's L2).
__global__ __launch_bounds__(256) void gemm1_kernel(
    const unsigned short* __restrict__ A,    // [16384,1024] bf16 bits
    const unsigned short* __restrict__ Bt,   // [1024,1024]  bf16 bits
    const float* __restrict__ Ubias,         // fp32, len 1024
    unsigned short* __restrict__ T) {
  __shared__ __align__(16) unsigned short As[128 * 64];
  __shared__ __align__(16) unsigned short Bs[128 * 64];
  int m0 = blockIdx.x * 128, n0 = blockIdx.y * 128;
  int tid = threadIdx.x;
  int lane = tid & 63, wave = tid >> 6;
  int quad = lane >> 4, lrow = lane & 15;
  int wm = wave >> 1, wn = wave & 1;

  floatx4 acc[4][4] = {};
  gemm_core_swz(A, Bt, m0, n0, As, Bs, acc);

  // C/D layout: col = lane&15, row = quad*4 + reg  [m89-verified]
  #pragma unroll
  for (int mt = 0; mt < 4; ++mt)
    #pragma unroll
    for (int nt = 0; nt < 4; ++nt) {
      int row = m0 + wm * 64 + mt * 16 + quad * 4;
      int col = n0 + wn * 64 + nt * 16 + lrow;
      float bias = Ubias[col];
      #pragma unroll
      for (int rr = 0; rr < 4; ++rr)
        T[(size_t)(row + rr) * D_DIM + col] = f2bf(acc[mt][nt][rr] + bias);
    }
}

// ---- GEMM2: out[b,x,y] = sum_k T[b,x,k]*Hbf[b,y,k] + linD[b,x] + linH[b,y] --
// grid (32, 16): id%8 = b%8 -> each batch's 16 blocks on one XCD;
// T[b]+H[b] = 4 MB ~ per-XCD L2.
__global__ __launch_bounds__(256) void gemm2_kernel(
    const unsigned short* __restrict__ Tg,   // [32*512,1024]
    const unsigned short* __restrict__ Hbf,  // [32*512,1024]
    const float* __restrict__ linD, const float* __restrict__ linH,
    float* __restrict__ out) {               // [32,512,512]
  __shared__ __align__(16) unsigned short As[128 * 64];
  __shared__ __align__(16) unsigned short Bs[128 * 64];
  int b = blockIdx.x;
  int t = blockIdx.y;
  int m0 = (t >> 2) * 128, n0 = (t & 3) * 128;
  const unsigned short* A = Tg + (size_t)b * 512 * D_DIM;
  const unsigned short* Bt = Hbf + (size_t)b * 512 * D_DIM;
  int tid = threadIdx.x;
  int lane = tid & 63, wave = tid >> 6;
  int quad = lane >> 4, lrow = lane & 15;
  int wm = wave >> 1, wn = wave & 1;

  floatx4 acc[4][4] = {};
  gemm_core_swz(A, Bt, m0, n0, As, Bs, acc);

  #pragma unroll
  for (int mt = 0; mt < 4; ++mt)
    #pragma unroll
    for (int nt = 0; nt < 4; ++nt) {
      int row = m0 + wm * 64 + mt * 16 + quad * 4;
      int col = n0 + wn * 64 + nt * 16 + lrow;
      float lh = linH[b * 512 + col];
      #pragma unroll
      for (int rr = 0; rr < 4; ++rr) {
        float v = acc[mt][nt][rr] + linD[b * 512 + row + rr] + lh;
        out[((size_t)b * 512 + row + rr) * 512 + col] = v;
      }
    }
}

extern "C" void kernel_launch(void* const* d_in, const int* in_sizes, int n_in,
                              void* d_out, int out_size, void* d_ws, size_t ws_size,
                              hipStream_t stream) {
  const float* D = (const float*)d_in[0];
  const float* H = (const float*)d_in[1];
  const float* U = (const float*)d_in[2];   // [1025,1024]
  const float* W = (const float*)d_in[3];   // [2049]
  float* out = (float*)d_out;

  char* ws = (char*)d_ws;
  unsigned short* Dbf = (unsigned short*)ws; ws += (size_t)ROWS * D_DIM * 2;   // 32 MB
  unsigned short* Hbf = (unsigned short*)ws; ws += (size_t)ROWS * D_DIM * 2;   // 32 MB
  unsigned short* Tbf = (unsigned short*)ws; ws += (size_t)ROWS * D_DIM * 2;   // 32 MB
  unsigned short* Ut  = (unsigned short*)ws; ws += (size_t)D_DIM * D_DIM * 2;  //  2 MB
  float* linD = (float*)ws;                  ws += (size_t)ROWS * 4;
  float* linH = (float*)ws;                  ws += (size_t)ROWS * 4;

  cast_rows_kernel<<<dim3(2 * ROWS), 256, 0, stream>>>(D, H, W, Dbf, Hbf, linD, linH);
  transU_kernel<<<dim3(32, 32), 256, 0, stream>>>(U, Ut);
  gemm1_kernel<<<dim3(128, 8), 256, 0, stream>>>(Dbf, Ut, U + (size_t)D_DIM * D_DIM, Tbf);
  gemm2_kernel<<<dim3(32, 16), 256, 0, stream>>>(Tbf, Hbf, linD, linH, out);
}